// Round 19
// baseline (402.021 us; speedup 1.0000x reference)
//
#include <hip/hip_runtime.h>
#include <hip/hip_bf16.h>
#include <hip/hip_fp16.h>

// GCN forward: 5x (agg + linear + relu fused) + segment_max pool + MLP head.
// N=100000, E=1600000, C=32, G=128.
//
// R19 = R18 + scheduling tweaks only (no kernel-body changes):
//   - gcn_layer grid = N/8 blocks (one 8-node tile each) instead of 2048
//     grid-stride: kills the ~15% tail-quantization (occ 66->~80%).
//   - pool PCHUNK 128->64: halves the serial per-thread load chain.
// Pipeline (11 dispatches): bin_count(+zero pooled) -> colscan ->
//   bin_scatter -> build_csr_embed(packed, sentinels) -> gcn_layer1
//   (flavor-factorized: t[v][f] edge hist + 32x17 WE matmul; packed[] is
//   L2-resident 400KB) -> 4x gcn_layer -> pool -> head.
// NOTE R15: grid.sync mega-kernel 10x slower (cross-XCD sync ~300us) — never.
// NOTE R16: never run the head on a single tail block (110us).
// Layer FETCH 56MB = 8 XCDs x 6.4MB COMPULSORY replication (R18 analysis) —
// footprint tricks gain nothing; layer is at its latency/issue floor.
// gcn_layer (layers 2-5): FROZEN R8 shape — 32-lane group per node, one int4
// index load -> 4 independent one-row (64B) fp16 gathers, in-register 32x32
// matmul via __shfl. R6/R7/R9/R13 rewrites all regressed 20-750%. Do not touch.

#define CDIM 32
#define BSHIFT 7
#define BSPAN 128
#define MAXBUK 800      // >= ceil(100000/128)=782
#define CHUNK 12800
#define BCAP 2560       // per-bucket capacity in pairs[] (mean 2046, 11 sigma)
#define CSRCAP 3072     // per-bucket csr capacity (>= BCAP + 3*128 padding)
#define PCHUNK 64
#define NFLAV 17

// per-chunk LDS histogram -> counts[chunk*MAXBUK + b]; block 0 zeroes pooled
__global__ void __launch_bounds__(256) bin_count(
    const int* __restrict__ edst, int* __restrict__ counts,
    unsigned* __restrict__ pooled, int E, int nbuk, int G) {
    __shared__ int hist[MAXBUK];
    int t = threadIdx.x;
    if (blockIdx.x == 0) {
        for (int i = t; i < G * CDIM; i += 256) pooled[i] = 0u;
    }
    int base = blockIdx.x * CHUNK;
    int n = min(CHUNK, E - base);
    for (int i = t; i < nbuk; i += 256) hist[i] = 0;
    __syncthreads();
    for (int i = t; i < n; i += 256)
        atomicAdd(&hist[edst[base + i] >> BSHIFT], 1);
    __syncthreads();
    for (int b = t; b < nbuk; b += 256)
        counts[blockIdx.x * MAXBUK + b] = hist[b];
}

// per bucket: exclusive scan of its chunk-counts -> runpre, total -> btot
__global__ void __launch_bounds__(256) colscan(
    const int* __restrict__ counts, int* __restrict__ runpre,
    int* __restrict__ btot, int nchunks) {
    __shared__ int s[256];
    int b = blockIdx.x, t = threadIdx.x;
    int v = (t < nchunks) ? counts[t * MAXBUK + b] : 0;
    s[t] = v;
    __syncthreads();
    for (int d = 1; d < 256; d <<= 1) {
        int x = (t >= d) ? s[t - d] : 0;
        __syncthreads();
        s[t] += x;
        __syncthreads();
    }
    if (t < nchunks) runpre[t * MAXBUK + b] = s[t] - v;  // exclusive
    if (t == 255) btot[b] = s[255];
}

// scatter edges into pairs[b*BCAP + runpre + lds_cursor]; no global atomics
__global__ void __launch_bounds__(256) bin_scatter(
    const int* __restrict__ esrc, const int* __restrict__ edst,
    const int* __restrict__ runpre, unsigned* __restrict__ pairs,
    int E, int nbuk) {
    __shared__ int lcur[MAXBUK];
    int t = threadIdx.x;
    int base = blockIdx.x * CHUNK;
    int n = min(CHUNK, E - base);
    for (int b = t; b < nbuk; b += 256)
        lcur[b] = runpre[blockIdx.x * MAXBUK + b];
    __syncthreads();
    for (int i = t; i < n; i += 256) {
        int d = edst[base + i];
        int s = esrc[base + i];
        int b = d >> BSHIFT;
        int pos = atomicAdd(&lcur[b], 1);
        pairs[(size_t)b * BCAP + pos] =
            ((unsigned)(d & (BSPAN - 1)) << 20) | (unsigned)s;
    }
}

// per bucket: hist -> cnt/dinvx/packed; LDS scan -> bucket-local offsets4;
// scatter src into csr; pad to x4 with sentinel N; write sentinel rows.
__global__ void __launch_bounds__(256) build_csr_embed(
    const unsigned* __restrict__ pairs, const int* __restrict__ btot,
    const int* __restrict__ x_idx,
    int* __restrict__ cnt, float* __restrict__ dinvx,
    unsigned* __restrict__ packed,
    int* __restrict__ offsets4, int* __restrict__ csr,
    __half* __restrict__ hA, __half* __restrict__ hB, int N) {
    __shared__ int h[BSPAN];
    __shared__ int p[BSPAN];
    __shared__ int lcur[BSPAN];
    __shared__ int obase[BSPAN];
    int b = blockIdx.x, t = threadIdx.x;
    int v0 = b << BSHIFT;
    if (t < BSPAN) h[t] = 0;
    __syncthreads();
    size_t p0 = (size_t)b * BCAP;
    size_t p1 = p0 + btot[b];
    for (size_t i = p0 + t; i < p1; i += 256)
        atomicAdd(&h[pairs[i] >> 20], 1);
    __syncthreads();
    int own = 0;
    if (t < BSPAN) {
        int v = v0 + t;
        int c = (v < N) ? h[t] : 0;
        float dv = rsqrtf((float)c + 1.0f);
        if (v < N) {
            cnt[v] = c;
            dinvx[v] = dv;
            packed[v] = (unsigned)__half_as_ushort(__float2half(dv)) |
                        ((unsigned)x_idx[v] << 16);
        }
        own = (c + 3) & ~3;
        p[t] = own;
    }
    __syncthreads();
    // Hillis-Steele inclusive scan over 128 entries
    for (int d = 1; d < BSPAN; d <<= 1) {
        int x = 0;
        if (t < BSPAN && t >= d) x = p[t - d];
        __syncthreads();
        if (t < BSPAN) p[t] += x;
        __syncthreads();
    }
    if (t < BSPAN) {
        int o = b * CSRCAP + p[t] - own;  // exclusive, bucket-local
        int v = v0 + t;
        if (v < N) offsets4[v] = o;
        lcur[t] = o;
        obase[t] = o;
    }
    __syncthreads();
    for (size_t i = p0 + t; i < p1; i += 256) {
        unsigned pk = pairs[i];
        int pos = atomicAdd(&lcur[pk >> 20], 1);
        csr[pos] = (int)(pk & 0xFFFFFu);
    }
    __syncthreads();
    if (t < BSPAN) {
        int v = v0 + t;
        if (v < N) {
            int e = lcur[t];  // == offsets4[v] + cnt[v]
            int e1 = obase[t] + ((e - obase[t] + 3) & ~3);
            for (; e < e1; ++e) csr[e] = N;  // pad -> zero feature row
        }
    }
    if (b == 0 && t < CDIM) {  // sentinel row N in both buffers
        if (t == 0) {
            dinvx[N] = 0.f;
            packed[N] = 0u;
        }
        hA[N * CDIM + t] = __float2half(0.f);
        hB[N * CDIM + t] = __float2half(0.f);
    }
}

// Layer 1, flavor-factorized. One block per bucket (128 nodes).
__global__ void __launch_bounds__(256) gcn_layer1(
    const unsigned* __restrict__ pairs, const int* __restrict__ btot,
    const unsigned* __restrict__ packed,
    const float* __restrict__ W1, const float* __restrict__ b1,
    const float* __restrict__ ew, __half* __restrict__ out, int N) {
    __shared__ float WE[CDIM * NFLAV];     // WE[c*17+f] = sum_k W1[c][k]*ew[f][k]
    __shared__ float tt[BSPAN * NFLAV];    // t[node][flavor]
    __shared__ float dvs[BSPAN];
    int t = threadIdx.x;
    int b = blockIdx.x;
    int v0 = b << BSHIFT;

    for (int i = t; i < CDIM * NFLAV; i += 256) {
        int c = i / NFLAV, f = i % NFLAV;
        float a = 0.f;
        #pragma unroll
        for (int k = 0; k < CDIM; ++k)
            a += W1[c * CDIM + k] * ew[f * CDIM + k];
        WE[i] = a;
    }
    for (int i = t; i < BSPAN * NFLAV; i += 256) tt[i] = 0.f;
    __syncthreads();
    if (t < BSPAN) {
        int v = v0 + t;
        float dv = 0.f;
        if (v < N) {
            unsigned pk = packed[v];
            dv = __half2float(__ushort_as_half((unsigned short)(pk & 0xFFFFu)));
            tt[t * NFLAV + (pk >> 16)] = dv;
        }
        dvs[t] = dv;
    }
    __syncthreads();
    size_t p0 = (size_t)b * BCAP;
    size_t p1 = p0 + btot[b];
    for (size_t i = p0 + t; i < p1; i += 256) {
        unsigned pk = pairs[i];
        int dl = (int)(pk >> 20);
        unsigned sp = packed[pk & 0xFFFFFu];
        float dv = __half2float(__ushort_as_half((unsigned short)(sp & 0xFFFFu)));
        atomicAdd(&tt[dl * NFLAV + (sp >> 16)], dv);
    }
    __syncthreads();
    int c = t & 31, grp = t >> 5;
    for (int j = 0; j < 16; ++j) {
        int dl = grp * 16 + j;
        int v = v0 + dl;
        if (v >= N) break;
        float dv = dvs[dl];
        float s = 0.f;
        #pragma unroll
        for (int f = 0; f < NFLAV; ++f)
            s = fmaf(tt[dl * NFLAV + f], WE[c * NFLAV + f], s);
        float o = fmaxf(fmaf(dv, s, b1[c]), 0.f) * dv;  // relu + scale_next
        out[v * CDIM + c] = __float2half(o);
    }
}

// Fused GCN layer (FROZEN R8 shape — proven 44us). 32-lane group per node;
// fp16 features, fp32 math. One int4 index load -> 4 independent row gathers.
__global__ void __launch_bounds__(256) gcn_layer(
    const __half* __restrict__ ht, const float* __restrict__ dinvx,
    const int* __restrict__ offsets4, const int* __restrict__ cnt,
    const int* __restrict__ csr, const float* __restrict__ W,
    const float* __restrict__ bias, __half* __restrict__ out,
    int N, int scale_next) {
    int c = threadIdx.x & 31;
    int grp = threadIdx.x >> 5;  // 0..7

    float w[CDIM];
    {
        const float4* Wrow = reinterpret_cast<const float4*>(W + c * CDIM);
        #pragma unroll
        for (int q = 0; q < CDIM / 4; ++q) {
            float4 t = Wrow[q];
            w[4 * q + 0] = t.x;
            w[4 * q + 1] = t.y;
            w[4 * q + 2] = t.z;
            w[4 * q + 3] = t.w;
        }
    }
    float bc = bias[c];

    for (int v0 = blockIdx.x * 8; v0 < N; v0 += gridDim.x * 8) {
        int v = v0 + grp;
        if (v >= N) continue;  // uniform across the 32-lane group
        float dv = dinvx[v];
        float acc = __half2float(ht[v * CDIM + c]);
        int e = offsets4[v];
        int e1 = e + ((cnt[v] + 3) & ~3);
        for (; e < e1; e += 4) {
            int4 s4 = *reinterpret_cast<const int4*>(&csr[e]);
            float a0 = __half2float(ht[s4.x * CDIM + c]);
            float a1 = __half2float(ht[s4.y * CDIM + c]);
            float a2 = __half2float(ht[s4.z * CDIM + c]);
            float a3 = __half2float(ht[s4.w * CDIM + c]);
            acc += (a0 + a1) + (a2 + a3);
        }
        float aggv = dv * acc;  // true aggregation value, channel c
        float o = bc;
        #pragma unroll
        for (int k = 0; k < CDIM; ++k)
            o = fmaf(__shfl(aggv, k, 32), w[k], o);
        o = fmaxf(o, 0.f);
        if (scale_next) o *= dv;
        out[v * CDIM + c] = __float2half(o);
    }
}

// chunked segment-max over sorted batch; h >= 0 so uint-bit atomicMax is valid
__global__ void pool_kernel(const __half* __restrict__ h, const int* __restrict__ batch,
                            unsigned* __restrict__ pooled, int N) {
    __shared__ int sb[8 * PCHUNK];
    int t = threadIdx.x;
    int chunk0 = blockIdx.x * 8;
    int sbase = chunk0 * PCHUNK;
    for (int i = t; i < 8 * PCHUNK; i += 256)
        sb[i] = (sbase + i < N) ? batch[sbase + i] : -1;
    __syncthreads();
    int c = t & 31, cs = t >> 5;
    int i0 = (chunk0 + cs) * PCHUNK;
    if (i0 >= N) return;
    int curg = sb[cs * PCHUNK];
    float m = -1.0f;  // sentinel: nothing accumulated (h values are >= 0)
    for (int k = 0; k < PCHUNK; ++k) {
        int i = i0 + k;
        if (i >= N) break;
        int g = sb[cs * PCHUNK + k];
        float v = __half2float(h[i * CDIM + c]);
        if (g != curg) {
            if (m >= 0.f) atomicMax(&pooled[curg * CDIM + c], __float_as_uint(m));
            curg = g;
            m = v;
        } else {
            m = fmaxf(m, v);
        }
    }
    if (m >= 0.f && curg >= 0) atomicMax(&pooled[curg * CDIM + c], __float_as_uint(m));
}

// 32-lane group per graph; coalesced float4 weight rows + __shfl matmul.
__global__ void __launch_bounds__(256) head_kernel(
    const float* __restrict__ pooled,
    const float* __restrict__ d0_w, const float* __restrict__ d0_b,
    const float* __restrict__ dense_w, const float* __restrict__ dense_b,
    const float* __restrict__ fin_w, const float* __restrict__ fin_b,
    float* __restrict__ out, int G) {
    int c = threadIdx.x & 31;
    int grp = threadIdx.x >> 5;
    int g = blockIdx.x * 8 + grp;
    if (g >= G) return;

    float x = pooled[g * CDIM + c];  // lane c holds channel c

    const float* Ws[4] = {d0_w, dense_w, dense_w + CDIM * CDIM,
                          dense_w + 2 * CDIM * CDIM};
    const float* bs[4] = {d0_b, dense_b, dense_b + CDIM, dense_b + 2 * CDIM};
    for (int l = 0; l < 4; ++l) {
        float w[CDIM];
        const float4* Wrow = reinterpret_cast<const float4*>(Ws[l] + c * CDIM);
        #pragma unroll
        for (int q = 0; q < CDIM / 4; ++q) {
            float4 t = Wrow[q];
            w[4 * q + 0] = t.x;
            w[4 * q + 1] = t.y;
            w[4 * q + 2] = t.z;
            w[4 * q + 3] = t.w;
        }
        float acc = bs[l][c];
        #pragma unroll
        for (int k = 0; k < CDIM; ++k)
            acc = fmaf(__shfl(x, k, 32), w[k], acc);
        x = fmaxf(acc, 0.f);
    }
    // logits: butterfly reduce partial products across the 32-lane group
    float p0 = x * fin_w[c];
    float p1 = x * fin_w[CDIM + c];
    #pragma unroll
    for (int d = 16; d > 0; d >>= 1) {
        p0 += __shfl_xor(p0, d, 32);
        p1 += __shfl_xor(p1, d, 32);
    }
    float l0 = p0 + fin_b[0], l1 = p1 + fin_b[1];
    float mm = fmaxf(l0, l1);
    float lse = mm + logf(expf(l0 - mm) + expf(l1 - mm));
    if (c == 0) {
        out[g * 2 + 0] = l0 - lse;
        out[g * 2 + 1] = l1 - lse;
    }
}

extern "C" void kernel_launch(void* const* d_in, const int* in_sizes, int n_in,
                              void* d_out, int out_size, void* d_ws, size_t ws_size,
                              hipStream_t stream) {
    const int* x_idx = (const int*)d_in[0];
    const int* eidx = (const int*)d_in[1];
    const int* batch = (const int*)d_in[2];
    const float* embed_w = (const float*)d_in[3];
    const float* conv_w = (const float*)d_in[4];
    const float* conv_b = (const float*)d_in[5];
    const float* d0_w = (const float*)d_in[6];
    const float* d0_b = (const float*)d_in[7];
    const float* dense_w = (const float*)d_in[8];
    const float* dense_b = (const float*)d_in[9];
    const float* fin_w = (const float*)d_in[10];
    const float* fin_b = (const float*)d_in[11];

    int N = in_sizes[0];
    int E = in_sizes[1] / 2;
    int G = out_size / 2;
    const int* esrc = eidx;
    const int* edst = eidx + E;
    int nbuk = (N + BSPAN - 1) >> BSHIFT;  // 782
    int CB = (E + CHUNK - 1) / CHUNK;      // 125 chunks (<= 256 for colscan)

    char* ws = (char*)d_ws;
    size_t off = 0;
    auto take = [&](size_t bytes) -> char* {
        char* p = ws + off;
        off = (off + bytes + 255) & ~(size_t)255;
        return p;
    };
    int* cnt = (int*)take((size_t)N * 4);
    float* dinvx = (float*)take((size_t)(N + 1) * 4);
    unsigned* packed = (unsigned*)take((size_t)(N + 1) * 4);
    int* offsets4 = (int*)take((size_t)N * 4);
    int* btot = (int*)take(MAXBUK * 4);
    int* counts = (int*)take((size_t)CB * MAXBUK * 4);
    int* runpre = (int*)take((size_t)CB * MAXBUK * 4);
    unsigned* pairs = (unsigned*)take((size_t)MAXBUK * BCAP * 4);
    int* csr = (int*)take((size_t)MAXBUK * CSRCAP * 4);
    __half* hA = (__half*)take((size_t)(N + 1) * CDIM * 2);
    __half* hB = (__half*)take((size_t)(N + 1) * CDIM * 2);
    unsigned* pooled = (unsigned*)take((size_t)G * CDIM * 4);
    (void)ws_size;
    (void)n_in;

    bin_count<<<CB, 256, 0, stream>>>(edst, counts, pooled, E, nbuk, G);
    colscan<<<nbuk, 256, 0, stream>>>(counts, runpre, btot, CB);
    bin_scatter<<<CB, 256, 0, stream>>>(esrc, edst, runpre, pairs, E, nbuk);
    build_csr_embed<<<nbuk, 256, 0, stream>>>(pairs, btot, x_idx,
                                              cnt, dinvx, packed,
                                              offsets4, csr, hA, hB, N);

    // layer 1: flavor-factorized (writes hB)
    gcn_layer1<<<nbuk, 256, 0, stream>>>(pairs, btot, packed,
                                         conv_w + 0 * CDIM * CDIM,
                                         conv_b + 0 * CDIM, embed_w, hB, N);

    int LB = (N + 7) / 8;  // one 8-node tile per block: no grid-stride tail
    gcn_layer<<<LB, 256, 0, stream>>>(hB, dinvx, offsets4, cnt, csr,
                                      conv_w + 1 * CDIM * CDIM, conv_b + 1 * CDIM, hA, N, 1);
    gcn_layer<<<LB, 256, 0, stream>>>(hA, dinvx, offsets4, cnt, csr,
                                      conv_w + 2 * CDIM * CDIM, conv_b + 2 * CDIM, hB, N, 1);
    gcn_layer<<<LB, 256, 0, stream>>>(hB, dinvx, offsets4, cnt, csr,
                                      conv_w + 3 * CDIM * CDIM, conv_b + 3 * CDIM, hA, N, 1);
    gcn_layer<<<LB, 256, 0, stream>>>(hA, dinvx, offsets4, cnt, csr,
                                      conv_w + 4 * CDIM * CDIM, conv_b + 4 * CDIM, hB, N, 0);

    int nchunks = (N + PCHUNK - 1) / PCHUNK;
    pool_kernel<<<(nchunks + 7) / 8, 256, 0, stream>>>(hB, batch, pooled, N);
    head_kernel<<<(G + 7) / 8, 256, 0, stream>>>((const float*)pooled, d0_w, d0_b,
                                                 dense_w, dense_b, fin_w, fin_b,
                                                 (float*)d_out, G);
}

// Round 20
// 275.640 us; speedup vs baseline: 1.4585x; 1.4585x over previous
//
#include <hip/hip_runtime.h>
#include <hip/hip_bf16.h>
#include <hip/hip_fp16.h>

// GCN forward: 5x (agg + linear + relu fused) + segment_max pool + MLP head.
// N=100000, E=1600000, C=32, G=128.
//
// R20 = R18 (proven 296.5us) + PCHUNK 64 pool tweak only.
// NOTE R19: gcn_layer grid MUST stay 2048 grid-stride — one-tile-per-block
// (12500 blocks) made layers 43.5->77us (+75%): per-block weight preload
// stops amortizing (~6 tiles/block -> 1). Grid shape is FROZEN at 2048.
// Pipeline (11 dispatches): bin_count(+zero pooled) -> colscan ->
//   bin_scatter -> build_csr_embed(packed, sentinels) -> gcn_layer1
//   (flavor-factorized: t[v][f] edge hist + 32x17 WE matmul; packed[] is
//   L2-resident 400KB) -> 4x gcn_layer -> pool -> head.
// NOTE R15: grid.sync mega-kernel 10x slower (cross-XCD sync ~300us) — never.
// NOTE R16: never run the head on a single tail block (110us).
// Layer FETCH 56MB = 8 XCDs x 6.4MB COMPULSORY replication — footprint
// tricks gain nothing; layer is at its latency/issue floor.
// gcn_layer (layers 2-5): FROZEN R8 shape — 32-lane group per node, one int4
// index load -> 4 independent one-row (64B) fp16 gathers, in-register 32x32
// matmul via __shfl. R6/R7/R9/R13 rewrites all regressed 20-750%. Do not touch.

#define CDIM 32
#define BSHIFT 7
#define BSPAN 128
#define MAXBUK 800      // >= ceil(100000/128)=782
#define CHUNK 12800
#define BCAP 2560       // per-bucket capacity in pairs[] (mean 2046, 11 sigma)
#define CSRCAP 3072     // per-bucket csr capacity (>= BCAP + 3*128 padding)
#define PCHUNK 64
#define NFLAV 17

// per-chunk LDS histogram -> counts[chunk*MAXBUK + b]; block 0 zeroes pooled
__global__ void __launch_bounds__(256) bin_count(
    const int* __restrict__ edst, int* __restrict__ counts,
    unsigned* __restrict__ pooled, int E, int nbuk, int G) {
    __shared__ int hist[MAXBUK];
    int t = threadIdx.x;
    if (blockIdx.x == 0) {
        for (int i = t; i < G * CDIM; i += 256) pooled[i] = 0u;
    }
    int base = blockIdx.x * CHUNK;
    int n = min(CHUNK, E - base);
    for (int i = t; i < nbuk; i += 256) hist[i] = 0;
    __syncthreads();
    for (int i = t; i < n; i += 256)
        atomicAdd(&hist[edst[base + i] >> BSHIFT], 1);
    __syncthreads();
    for (int b = t; b < nbuk; b += 256)
        counts[blockIdx.x * MAXBUK + b] = hist[b];
}

// per bucket: exclusive scan of its chunk-counts -> runpre, total -> btot
__global__ void __launch_bounds__(256) colscan(
    const int* __restrict__ counts, int* __restrict__ runpre,
    int* __restrict__ btot, int nchunks) {
    __shared__ int s[256];
    int b = blockIdx.x, t = threadIdx.x;
    int v = (t < nchunks) ? counts[t * MAXBUK + b] : 0;
    s[t] = v;
    __syncthreads();
    for (int d = 1; d < 256; d <<= 1) {
        int x = (t >= d) ? s[t - d] : 0;
        __syncthreads();
        s[t] += x;
        __syncthreads();
    }
    if (t < nchunks) runpre[t * MAXBUK + b] = s[t] - v;  // exclusive
    if (t == 255) btot[b] = s[255];
}

// scatter edges into pairs[b*BCAP + runpre + lds_cursor]; no global atomics
__global__ void __launch_bounds__(256) bin_scatter(
    const int* __restrict__ esrc, const int* __restrict__ edst,
    const int* __restrict__ runpre, unsigned* __restrict__ pairs,
    int E, int nbuk) {
    __shared__ int lcur[MAXBUK];
    int t = threadIdx.x;
    int base = blockIdx.x * CHUNK;
    int n = min(CHUNK, E - base);
    for (int b = t; b < nbuk; b += 256)
        lcur[b] = runpre[blockIdx.x * MAXBUK + b];
    __syncthreads();
    for (int i = t; i < n; i += 256) {
        int d = edst[base + i];
        int s = esrc[base + i];
        int b = d >> BSHIFT;
        int pos = atomicAdd(&lcur[b], 1);
        pairs[(size_t)b * BCAP + pos] =
            ((unsigned)(d & (BSPAN - 1)) << 20) | (unsigned)s;
    }
}

// per bucket: hist -> cnt/dinvx/packed; LDS scan -> bucket-local offsets4;
// scatter src into csr; pad to x4 with sentinel N; write sentinel rows.
__global__ void __launch_bounds__(256) build_csr_embed(
    const unsigned* __restrict__ pairs, const int* __restrict__ btot,
    const int* __restrict__ x_idx,
    int* __restrict__ cnt, float* __restrict__ dinvx,
    unsigned* __restrict__ packed,
    int* __restrict__ offsets4, int* __restrict__ csr,
    __half* __restrict__ hA, __half* __restrict__ hB, int N) {
    __shared__ int h[BSPAN];
    __shared__ int p[BSPAN];
    __shared__ int lcur[BSPAN];
    __shared__ int obase[BSPAN];
    int b = blockIdx.x, t = threadIdx.x;
    int v0 = b << BSHIFT;
    if (t < BSPAN) h[t] = 0;
    __syncthreads();
    size_t p0 = (size_t)b * BCAP;
    size_t p1 = p0 + btot[b];
    for (size_t i = p0 + t; i < p1; i += 256)
        atomicAdd(&h[pairs[i] >> 20], 1);
    __syncthreads();
    int own = 0;
    if (t < BSPAN) {
        int v = v0 + t;
        int c = (v < N) ? h[t] : 0;
        float dv = rsqrtf((float)c + 1.0f);
        if (v < N) {
            cnt[v] = c;
            dinvx[v] = dv;
            packed[v] = (unsigned)__half_as_ushort(__float2half(dv)) |
                        ((unsigned)x_idx[v] << 16);
        }
        own = (c + 3) & ~3;
        p[t] = own;
    }
    __syncthreads();
    // Hillis-Steele inclusive scan over 128 entries
    for (int d = 1; d < BSPAN; d <<= 1) {
        int x = 0;
        if (t < BSPAN && t >= d) x = p[t - d];
        __syncthreads();
        if (t < BSPAN) p[t] += x;
        __syncthreads();
    }
    if (t < BSPAN) {
        int o = b * CSRCAP + p[t] - own;  // exclusive, bucket-local
        int v = v0 + t;
        if (v < N) offsets4[v] = o;
        lcur[t] = o;
        obase[t] = o;
    }
    __syncthreads();
    for (size_t i = p0 + t; i < p1; i += 256) {
        unsigned pk = pairs[i];
        int pos = atomicAdd(&lcur[pk >> 20], 1);
        csr[pos] = (int)(pk & 0xFFFFFu);
    }
    __syncthreads();
    if (t < BSPAN) {
        int v = v0 + t;
        if (v < N) {
            int e = lcur[t];  // == offsets4[v] + cnt[v]
            int e1 = obase[t] + ((e - obase[t] + 3) & ~3);
            for (; e < e1; ++e) csr[e] = N;  // pad -> zero feature row
        }
    }
    if (b == 0 && t < CDIM) {  // sentinel row N in both buffers
        if (t == 0) {
            dinvx[N] = 0.f;
            packed[N] = 0u;
        }
        hA[N * CDIM + t] = __float2half(0.f);
        hB[N * CDIM + t] = __float2half(0.f);
    }
}

// Layer 1, flavor-factorized. One block per bucket (128 nodes).
__global__ void __launch_bounds__(256) gcn_layer1(
    const unsigned* __restrict__ pairs, const int* __restrict__ btot,
    const unsigned* __restrict__ packed,
    const float* __restrict__ W1, const float* __restrict__ b1,
    const float* __restrict__ ew, __half* __restrict__ out, int N) {
    __shared__ float WE[CDIM * NFLAV];     // WE[c*17+f] = sum_k W1[c][k]*ew[f][k]
    __shared__ float tt[BSPAN * NFLAV];    // t[node][flavor]
    __shared__ float dvs[BSPAN];
    int t = threadIdx.x;
    int b = blockIdx.x;
    int v0 = b << BSHIFT;

    for (int i = t; i < CDIM * NFLAV; i += 256) {
        int c = i / NFLAV, f = i % NFLAV;
        float a = 0.f;
        #pragma unroll
        for (int k = 0; k < CDIM; ++k)
            a += W1[c * CDIM + k] * ew[f * CDIM + k];
        WE[i] = a;
    }
    for (int i = t; i < BSPAN * NFLAV; i += 256) tt[i] = 0.f;
    __syncthreads();
    if (t < BSPAN) {
        int v = v0 + t;
        float dv = 0.f;
        if (v < N) {
            unsigned pk = packed[v];
            dv = __half2float(__ushort_as_half((unsigned short)(pk & 0xFFFFu)));
            tt[t * NFLAV + (pk >> 16)] = dv;
        }
        dvs[t] = dv;
    }
    __syncthreads();
    size_t p0 = (size_t)b * BCAP;
    size_t p1 = p0 + btot[b];
    for (size_t i = p0 + t; i < p1; i += 256) {
        unsigned pk = pairs[i];
        int dl = (int)(pk >> 20);
        unsigned sp = packed[pk & 0xFFFFFu];
        float dv = __half2float(__ushort_as_half((unsigned short)(sp & 0xFFFFu)));
        atomicAdd(&tt[dl * NFLAV + (sp >> 16)], dv);
    }
    __syncthreads();
    int c = t & 31, grp = t >> 5;
    for (int j = 0; j < 16; ++j) {
        int dl = grp * 16 + j;
        int v = v0 + dl;
        if (v >= N) break;
        float dv = dvs[dl];
        float s = 0.f;
        #pragma unroll
        for (int f = 0; f < NFLAV; ++f)
            s = fmaf(tt[dl * NFLAV + f], WE[c * NFLAV + f], s);
        float o = fmaxf(fmaf(dv, s, b1[c]), 0.f) * dv;  // relu + scale_next
        out[v * CDIM + c] = __float2half(o);
    }
}

// Fused GCN layer (FROZEN R8 shape — proven 44us). 32-lane group per node;
// fp16 features, fp32 math. One int4 index load -> 4 independent row gathers.
__global__ void __launch_bounds__(256) gcn_layer(
    const __half* __restrict__ ht, const float* __restrict__ dinvx,
    const int* __restrict__ offsets4, const int* __restrict__ cnt,
    const int* __restrict__ csr, const float* __restrict__ W,
    const float* __restrict__ bias, __half* __restrict__ out,
    int N, int scale_next) {
    int c = threadIdx.x & 31;
    int grp = threadIdx.x >> 5;  // 0..7

    float w[CDIM];
    {
        const float4* Wrow = reinterpret_cast<const float4*>(W + c * CDIM);
        #pragma unroll
        for (int q = 0; q < CDIM / 4; ++q) {
            float4 t = Wrow[q];
            w[4 * q + 0] = t.x;
            w[4 * q + 1] = t.y;
            w[4 * q + 2] = t.z;
            w[4 * q + 3] = t.w;
        }
    }
    float bc = bias[c];

    for (int v0 = blockIdx.x * 8; v0 < N; v0 += gridDim.x * 8) {
        int v = v0 + grp;
        if (v >= N) continue;  // uniform across the 32-lane group
        float dv = dinvx[v];
        float acc = __half2float(ht[v * CDIM + c]);
        int e = offsets4[v];
        int e1 = e + ((cnt[v] + 3) & ~3);
        for (; e < e1; e += 4) {
            int4 s4 = *reinterpret_cast<const int4*>(&csr[e]);
            float a0 = __half2float(ht[s4.x * CDIM + c]);
            float a1 = __half2float(ht[s4.y * CDIM + c]);
            float a2 = __half2float(ht[s4.z * CDIM + c]);
            float a3 = __half2float(ht[s4.w * CDIM + c]);
            acc += (a0 + a1) + (a2 + a3);
        }
        float aggv = dv * acc;  // true aggregation value, channel c
        float o = bc;
        #pragma unroll
        for (int k = 0; k < CDIM; ++k)
            o = fmaf(__shfl(aggv, k, 32), w[k], o);
        o = fmaxf(o, 0.f);
        if (scale_next) o *= dv;
        out[v * CDIM + c] = __float2half(o);
    }
}

// chunked segment-max over sorted batch; h >= 0 so uint-bit atomicMax is valid
__global__ void pool_kernel(const __half* __restrict__ h, const int* __restrict__ batch,
                            unsigned* __restrict__ pooled, int N) {
    __shared__ int sb[8 * PCHUNK];
    int t = threadIdx.x;
    int chunk0 = blockIdx.x * 8;
    int sbase = chunk0 * PCHUNK;
    for (int i = t; i < 8 * PCHUNK; i += 256)
        sb[i] = (sbase + i < N) ? batch[sbase + i] : -1;
    __syncthreads();
    int c = t & 31, cs = t >> 5;
    int i0 = (chunk0 + cs) * PCHUNK;
    if (i0 >= N) return;
    int curg = sb[cs * PCHUNK];
    float m = -1.0f;  // sentinel: nothing accumulated (h values are >= 0)
    for (int k = 0; k < PCHUNK; ++k) {
        int i = i0 + k;
        if (i >= N) break;
        int g = sb[cs * PCHUNK + k];
        float v = __half2float(h[i * CDIM + c]);
        if (g != curg) {
            if (m >= 0.f) atomicMax(&pooled[curg * CDIM + c], __float_as_uint(m));
            curg = g;
            m = v;
        } else {
            m = fmaxf(m, v);
        }
    }
    if (m >= 0.f && curg >= 0) atomicMax(&pooled[curg * CDIM + c], __float_as_uint(m));
}

// 32-lane group per graph; coalesced float4 weight rows + __shfl matmul.
__global__ void __launch_bounds__(256) head_kernel(
    const float* __restrict__ pooled,
    const float* __restrict__ d0_w, const float* __restrict__ d0_b,
    const float* __restrict__ dense_w, const float* __restrict__ dense_b,
    const float* __restrict__ fin_w, const float* __restrict__ fin_b,
    float* __restrict__ out, int G) {
    int c = threadIdx.x & 31;
    int grp = threadIdx.x >> 5;
    int g = blockIdx.x * 8 + grp;
    if (g >= G) return;

    float x = pooled[g * CDIM + c];  // lane c holds channel c

    const float* Ws[4] = {d0_w, dense_w, dense_w + CDIM * CDIM,
                          dense_w + 2 * CDIM * CDIM};
    const float* bs[4] = {d0_b, dense_b, dense_b + CDIM, dense_b + 2 * CDIM};
    for (int l = 0; l < 4; ++l) {
        float w[CDIM];
        const float4* Wrow = reinterpret_cast<const float4*>(Ws[l] + c * CDIM);
        #pragma unroll
        for (int q = 0; q < CDIM / 4; ++q) {
            float4 t = Wrow[q];
            w[4 * q + 0] = t.x;
            w[4 * q + 1] = t.y;
            w[4 * q + 2] = t.z;
            w[4 * q + 3] = t.w;
        }
        float acc = bs[l][c];
        #pragma unroll
        for (int k = 0; k < CDIM; ++k)
            acc = fmaf(__shfl(x, k, 32), w[k], acc);
        x = fmaxf(acc, 0.f);
    }
    // logits: butterfly reduce partial products across the 32-lane group
    float p0 = x * fin_w[c];
    float p1 = x * fin_w[CDIM + c];
    #pragma unroll
    for (int d = 16; d > 0; d >>= 1) {
        p0 += __shfl_xor(p0, d, 32);
        p1 += __shfl_xor(p1, d, 32);
    }
    float l0 = p0 + fin_b[0], l1 = p1 + fin_b[1];
    float mm = fmaxf(l0, l1);
    float lse = mm + logf(expf(l0 - mm) + expf(l1 - mm));
    if (c == 0) {
        out[g * 2 + 0] = l0 - lse;
        out[g * 2 + 1] = l1 - lse;
    }
}

extern "C" void kernel_launch(void* const* d_in, const int* in_sizes, int n_in,
                              void* d_out, int out_size, void* d_ws, size_t ws_size,
                              hipStream_t stream) {
    const int* x_idx = (const int*)d_in[0];
    const int* eidx = (const int*)d_in[1];
    const int* batch = (const int*)d_in[2];
    const float* embed_w = (const float*)d_in[3];
    const float* conv_w = (const float*)d_in[4];
    const float* conv_b = (const float*)d_in[5];
    const float* d0_w = (const float*)d_in[6];
    const float* d0_b = (const float*)d_in[7];
    const float* dense_w = (const float*)d_in[8];
    const float* dense_b = (const float*)d_in[9];
    const float* fin_w = (const float*)d_in[10];
    const float* fin_b = (const float*)d_in[11];

    int N = in_sizes[0];
    int E = in_sizes[1] / 2;
    int G = out_size / 2;
    const int* esrc = eidx;
    const int* edst = eidx + E;
    int nbuk = (N + BSPAN - 1) >> BSHIFT;  // 782
    int CB = (E + CHUNK - 1) / CHUNK;      // 125 chunks (<= 256 for colscan)

    char* ws = (char*)d_ws;
    size_t off = 0;
    auto take = [&](size_t bytes) -> char* {
        char* p = ws + off;
        off = (off + bytes + 255) & ~(size_t)255;
        return p;
    };
    int* cnt = (int*)take((size_t)N * 4);
    float* dinvx = (float*)take((size_t)(N + 1) * 4);
    unsigned* packed = (unsigned*)take((size_t)(N + 1) * 4);
    int* offsets4 = (int*)take((size_t)N * 4);
    int* btot = (int*)take(MAXBUK * 4);
    int* counts = (int*)take((size_t)CB * MAXBUK * 4);
    int* runpre = (int*)take((size_t)CB * MAXBUK * 4);
    unsigned* pairs = (unsigned*)take((size_t)MAXBUK * BCAP * 4);
    int* csr = (int*)take((size_t)MAXBUK * CSRCAP * 4);
    __half* hA = (__half*)take((size_t)(N + 1) * CDIM * 2);
    __half* hB = (__half*)take((size_t)(N + 1) * CDIM * 2);
    unsigned* pooled = (unsigned*)take((size_t)G * CDIM * 4);
    (void)ws_size;
    (void)n_in;

    bin_count<<<CB, 256, 0, stream>>>(edst, counts, pooled, E, nbuk, G);
    colscan<<<nbuk, 256, 0, stream>>>(counts, runpre, btot, CB);
    bin_scatter<<<CB, 256, 0, stream>>>(esrc, edst, runpre, pairs, E, nbuk);
    build_csr_embed<<<nbuk, 256, 0, stream>>>(pairs, btot, x_idx,
                                              cnt, dinvx, packed,
                                              offsets4, csr, hA, hB, N);

    // layer 1: flavor-factorized (writes hB)
    gcn_layer1<<<nbuk, 256, 0, stream>>>(pairs, btot, packed,
                                         conv_w + 0 * CDIM * CDIM,
                                         conv_b + 0 * CDIM, embed_w, hB, N);

    int LB = 2048;  // FROZEN: grid-stride, ~6 tiles/block amortizes preload
    gcn_layer<<<LB, 256, 0, stream>>>(hB, dinvx, offsets4, cnt, csr,
                                      conv_w + 1 * CDIM * CDIM, conv_b + 1 * CDIM, hA, N, 1);
    gcn_layer<<<LB, 256, 0, stream>>>(hA, dinvx, offsets4, cnt, csr,
                                      conv_w + 2 * CDIM * CDIM, conv_b + 2 * CDIM, hB, N, 1);
    gcn_layer<<<LB, 256, 0, stream>>>(hB, dinvx, offsets4, cnt, csr,
                                      conv_w + 3 * CDIM * CDIM, conv_b + 3 * CDIM, hA, N, 1);
    gcn_layer<<<LB, 256, 0, stream>>>(hA, dinvx, offsets4, cnt, csr,
                                      conv_w + 4 * CDIM * CDIM, conv_b + 4 * CDIM, hB, N, 0);

    int nchunks = (N + PCHUNK - 1) / PCHUNK;
    pool_kernel<<<(nchunks + 7) / 8, 256, 0, stream>>>(hB, batch, pooled, N);
    head_kernel<<<(G + 7) / 8, 256, 0, stream>>>((const float*)pooled, d0_w, d0_b,
                                                 dense_w, dense_b, fin_w, fin_b,
                                                 (float*)d_out, G);
}